// Round 10
// baseline (224.402 us; speedup 1.0000x reference)
//
#include <hip/hip_runtime.h>
#include <stdint.h>

#define TPB 256
#define SPAN 256        // nodes per dest bucket (bucket = col>>8)
#define LSH 8           // log2(SPAN)
#define PART_B 256      // partition blocks (one per CU)
#define PART_T 1024     // threads in hist/partition/sort kernels
#define SCAN_T 1024
#define SCAN_B 4096     // elements per scan block (1024 thr x 4)
#define SORT_CAP 18432  // words of dynamic LDS sort buffer (72KB); Wreal ~16384±400
#define SENT 0xFFFFFFFFu
#define ALIGN_M 31u     // segment sizes rounded to 32 words = 128B lines

// ---------------------------------------------------------------------------
// GCN 3-layer forward on MI355X.
// R10: p_part line-ownership fix. R9 p_part: WRITE 67MB vs 25.6 payload
// (amp 2.6x) because (bucket,block) segments start at arbitrary offsets ->
// boundary lines co-written by blocks on different XCDs. Now segment sizes
// are rounded to 32 words in a PADDED scan (bpack offsets) so every 128B
// line is written by exactly one block; tails filled with SENT words that
// p_sort skips. A second UNPADDED scan provides dense csr/indptr offsets so
// the gather kernels are unchanged. If the padded layout exceeds bpack
// capacity (ws-dependent), scan3 auto-selects unpadded offsets = exact R9
// behavior (pad-fill no-op, no sentinels). R3 atomic-push fallback kept.
// ---------------------------------------------------------------------------

// ---------------- bucket partition ----------------

__global__ __launch_bounds__(PART_T) void p_hist(
    const int* __restrict__ col, uint32_t* __restrict__ H,
    int NB, int E, int PBE) {
    __shared__ uint32_t cnt[1024];
    for (int i = threadIdx.x; i < NB; i += PART_T) cnt[i] = 0u;
    __syncthreads();
    int blk = blockIdx.x;
    int s = blk * PBE, e = min(E, s + PBE);
    for (int i = s + threadIdx.x; i < e; i += PART_T)
        atomicAdd(&cnt[col[i] >> LSH], 1u);
    __syncthreads();
    for (int i = threadIdx.x; i < NB; i += PART_T)
        H[(size_t)i * PART_B + blk] = cnt[i];
}

// Scan phase 1 with optional per-element round-up (rmask=31 -> ceil to 32).
__global__ __launch_bounds__(SCAN_T) void k_scan1(
    const unsigned int* __restrict__ in, unsigned int* __restrict__ partial,
    unsigned int* __restrict__ bsum, int M, unsigned int rmask) {
    __shared__ unsigned int sm[SCAN_T];
    int tid  = threadIdx.x;
    int base = blockIdx.x * SCAN_B + tid * 4;
    unsigned int v0 = (base + 0 < M) ? ((in[base + 0] + rmask) & ~rmask) : 0u;
    unsigned int v1 = (base + 1 < M) ? ((in[base + 1] + rmask) & ~rmask) : 0u;
    unsigned int v2 = (base + 2 < M) ? ((in[base + 2] + rmask) & ~rmask) : 0u;
    unsigned int v3 = (base + 3 < M) ? ((in[base + 3] + rmask) & ~rmask) : 0u;
    unsigned int s = v0 + v1 + v2 + v3;
    sm[tid] = s;
    __syncthreads();
    for (int off = 1; off < SCAN_T; off <<= 1) {
        unsigned int t = (tid >= off) ? sm[tid - off] : 0u;
        __syncthreads();
        sm[tid] += t;
        __syncthreads();
    }
    unsigned int excl = sm[tid] - s;
    if (base + 0 < M) partial[base + 0] = excl;
    if (base + 1 < M) partial[base + 1] = excl + v0;
    if (base + 2 < M) partial[base + 2] = excl + v0 + v1;
    if (base + 3 < M) partial[base + 3] = excl + v0 + v1 + v2;
    if (tid == SCAN_T - 1) bsum[blockIdx.x] = sm[SCAN_T - 1];
}

// Scan phase 2; also emits grand total at bsum[nb].
__global__ void k_scan2(unsigned int* __restrict__ bsum, int nb) {
    if (threadIdx.x == 0 && blockIdx.x == 0) {
        unsigned int run = 0;
        for (int i = 0; i < nb; ++i) {
            unsigned int t = bsum[i];
            bsum[i] = run;
            run += t;
        }
        bsum[nb] = run;
    }
}

// Scan phase 3, A-side (bpack offsets): select padded (A) if totalA fits
// capacity, else fall back to unpadded (B) offsets. In-place on OA.
__global__ __launch_bounds__(TPB) void k_scan3A(
    unsigned int* __restrict__ OA, const unsigned int* __restrict__ bsumA,
    const unsigned int* __restrict__ partialB, const unsigned int* __restrict__ bsumB,
    int M, int E, unsigned int capA, int nbS) {
    unsigned int totalA = bsumA[nbS];
    bool ok = (totalA <= capA);
    int i = blockIdx.x * TPB + threadIdx.x;
    if (i < M) OA[i] = ok ? (OA[i] + bsumA[i / SCAN_B])
                          : (partialB[i] + bsumB[i / SCAN_B]);
    if (i == 0) OA[M] = ok ? totalA : (unsigned int)E;
}

// Scan phase 3, B-side (dense csr offsets). In-place on OB.
__global__ __launch_bounds__(TPB) void k_scan3B(
    unsigned int* __restrict__ OB, const unsigned int* __restrict__ bsumB,
    int M, int E) {
    int i = blockIdx.x * TPB + threadIdx.x;
    if (i < M) OB[i] = OB[i] + bsumB[i / SCAN_B];
    if (i == 0) OB[M] = (unsigned int)E;
}

// Partition: bpack[slot] = (row<<LSH)|ldest, bucket-grouped; fill segment
// tails with SENT (no-op when offsets are unpadded).
__global__ __launch_bounds__(PART_T) void p_part(
    const int* __restrict__ row, const int* __restrict__ col,
    const uint32_t* __restrict__ OA, uint32_t* __restrict__ bpack,
    int NB, int E, int PBE) {
    __shared__ uint32_t cur[1024];
    int blk = blockIdx.x;
    for (int i = threadIdx.x; i < NB; i += PART_T)
        cur[i] = OA[(size_t)i * PART_B + blk];
    __syncthreads();
    int s = blk * PBE, e = min(E, s + PBE);
    for (int i = s + threadIdx.x; i < e; i += PART_T) {
        int c = col[i];
        uint32_t slot = atomicAdd(&cur[c >> LSH], 1u);
        bpack[slot] = ((uint32_t)row[i] << LSH) | (uint32_t)(c & (SPAN - 1));
    }
    __syncthreads();
    // sentinel-fill tails up to next segment start (line-exclusive pad)
    for (int i = threadIdx.x; i < NB; i += PART_T) {
        uint32_t end = OA[(size_t)i * PART_B + blk + 1];
        for (uint32_t j = cur[i]; j < end; ++j) bpack[j] = SENT;
    }
}

// Per-bucket counting sort: padded bpack window -> dense csr_row window
// (base from unpadded OB), via LDS staging + coalesced writeout.
// Emits indptr + dinv. Sentinels skipped.
extern __shared__ uint32_t sort_buf[];
__global__ __launch_bounds__(PART_T) void p_sort(
    const uint32_t* __restrict__ bpack, const uint32_t* __restrict__ OA,
    const uint32_t* __restrict__ OB,
    int* __restrict__ csr_row, unsigned int* __restrict__ indptr,
    float* __restrict__ dinv, int NB, int N, int E) {
    __shared__ uint32_t hist[SPAN];
    __shared__ uint32_t cur[SPAN];
    int b = blockIdx.x;
    int t = threadIdx.x;
    if (t < SPAN) hist[t] = 0u;
    __syncthreads();
    uint32_t s  = OA[(size_t)b * PART_B];
    uint32_t e  = OA[(size_t)(b + 1) * PART_B];  // (NB)*PART_B == M valid
    uint32_t ub = OB[(size_t)b * PART_B];
    uint32_t ue = OB[(size_t)(b + 1) * PART_B];
    uint32_t Wreal = ue - ub;
    for (uint32_t i = s + t; i < e; i += PART_T) {
        uint32_t v = bpack[i];
        if (v != SENT) atomicAdd(&hist[v & (SPAN - 1)], 1u);
    }
    __syncthreads();
    if (t < SPAN) cur[t] = hist[t];
    __syncthreads();
    for (int off = 1; off < SPAN; off <<= 1) {  // Hillis-Steele inclusive scan
        uint32_t v = (t < SPAN && t >= off) ? cur[t - off] : 0u;
        __syncthreads();
        if (t < SPAN) cur[t] += v;
        __syncthreads();
    }
    if (t < SPAN) {
        uint32_t excl = cur[t] - hist[t];
        int n = b * SPAN + t;
        if (n < N) {
            indptr[n] = ub + excl;
            dinv[n]   = rsqrtf((float)(hist[t] + 1u));  // +1 = self loop
            if (n == N - 1) indptr[N] = (unsigned int)E;
        }
        cur[t] = excl;  // window-local cursor
    }
    __syncthreads();
    if (Wreal <= SORT_CAP) {
        for (uint32_t i = s + t; i < e; i += PART_T) {
            uint32_t v = bpack[i];
            if (v == SENT) continue;
            uint32_t slot = atomicAdd(&cur[v & (SPAN - 1)], 1u);
            sort_buf[slot] = v >> LSH;
        }
        __syncthreads();
        for (uint32_t j = t; j < Wreal; j += PART_T)
            csr_row[ub + j] = (int)sort_buf[j];
    } else {
        for (uint32_t i = s + t; i < e; i += PART_T) {
            uint32_t v = bpack[i];
            if (v == SENT) continue;
            uint32_t slot = atomicAdd(&cur[v & (SPAN - 1)], 1u);
            csr_row[ub + slot] = (int)(v >> LSH);
        }
    }
}

// ---------------- node / gather kernels (main path) ----------------

__global__ __launch_bounds__(TPB) void k_xw1d(
    const float* __restrict__ x, const float* __restrict__ W1,
    const float* __restrict__ dinv, float* __restrict__ dxw1, int N) {
    __shared__ float sW[512];  // 128 x 4
    for (int t = threadIdx.x; t < 512; t += TPB) sW[t] = W1[t];
    __syncthreads();
    int gid  = blockIdx.x * TPB + threadIdx.x;
    int node = gid >> 6;
    int lane = threadIdx.x & 63;
    if (node >= N) return;
    float2 v = *(const float2*)(x + (size_t)node * 128 + 2 * lane);
    const float* w0 = &sW[(2 * lane) * 4];
    const float* w1 = &sW[(2 * lane + 1) * 4];
    float a[4];
#pragma unroll
    for (int j = 0; j < 4; ++j) a[j] = v.x * w0[j] + v.y * w1[j];
#pragma unroll
    for (int off = 32; off > 0; off >>= 1) {
#pragma unroll
        for (int j = 0; j < 4; ++j) a[j] += __shfl_down(a[j], off);
    }
    if (lane == 0) {
        float d = dinv[node];
        *(float4*)(dxw1 + (size_t)node * 4) =
            make_float4(d * a[0], d * a[1], d * a[2], d * a[3]);
    }
}

__global__ __launch_bounds__(TPB) void k_gather44(
    const unsigned int* __restrict__ indptr, const int* __restrict__ csr_row,
    const float* __restrict__ dinv, const float* __restrict__ dxw_in,
    const float* __restrict__ b, const float* __restrict__ W,
    float* __restrict__ dxw_out, int N) {
    int gid  = blockIdx.x * TPB + threadIdx.x;
    int node = gid >> 4;
    int sub  = gid & 15;
    if (node >= N) return;
    int e0 = (int)indptr[node], e1 = (int)indptr[node + 1];
    float4 acc = make_float4(0.f, 0.f, 0.f, 0.f);
    for (int j = e0 + sub; j < e1; j += 16) {
        int r = csr_row[j];
        float4 m = *(const float4*)(dxw_in + (size_t)r * 4);
        acc.x += m.x; acc.y += m.y; acc.z += m.z; acc.w += m.w;
    }
#pragma unroll
    for (int off = 1; off < 16; off <<= 1) {
        acc.x += __shfl_xor(acc.x, off);
        acc.y += __shfl_xor(acc.y, off);
        acc.z += __shfl_xor(acc.z, off);
        acc.w += __shfl_xor(acc.w, off);
    }
    if (sub == 0) {
        float d = dinv[node];
        float4 sv = *(const float4*)(dxw_in + (size_t)node * 4);
        float h0 = fmaxf(d * (acc.x + sv.x) + b[0], 0.f);
        float h1 = fmaxf(d * (acc.y + sv.y) + b[1], 0.f);
        float h2 = fmaxf(d * (acc.z + sv.z) + b[2], 0.f);
        float h3 = fmaxf(d * (acc.w + sv.w) + b[3], 0.f);
        float o[4];
#pragma unroll
        for (int j = 0; j < 4; ++j)
            o[j] = h0 * W[0 * 4 + j] + h1 * W[1 * 4 + j] +
                   h2 * W[2 * 4 + j] + h3 * W[3 * 4 + j];
        *(float4*)(dxw_out + (size_t)node * 4) =
            make_float4(d * o[0], d * o[1], d * o[2], d * o[3]);
    }
}

__global__ __launch_bounds__(TPB) void k_gather42(
    const unsigned int* __restrict__ indptr, const int* __restrict__ csr_row,
    const float* __restrict__ dinv, const float* __restrict__ dxw_in,
    const float* __restrict__ b, const float* __restrict__ W,
    float* __restrict__ dxw_out, int N) {
    int gid  = blockIdx.x * TPB + threadIdx.x;
    int node = gid >> 4;
    int sub  = gid & 15;
    if (node >= N) return;
    int e0 = (int)indptr[node], e1 = (int)indptr[node + 1];
    float4 acc = make_float4(0.f, 0.f, 0.f, 0.f);
    for (int j = e0 + sub; j < e1; j += 16) {
        int r = csr_row[j];
        float4 m = *(const float4*)(dxw_in + (size_t)r * 4);
        acc.x += m.x; acc.y += m.y; acc.z += m.z; acc.w += m.w;
    }
#pragma unroll
    for (int off = 1; off < 16; off <<= 1) {
        acc.x += __shfl_xor(acc.x, off);
        acc.y += __shfl_xor(acc.y, off);
        acc.z += __shfl_xor(acc.z, off);
        acc.w += __shfl_xor(acc.w, off);
    }
    if (sub == 0) {
        float d = dinv[node];
        float4 sv = *(const float4*)(dxw_in + (size_t)node * 4);
        float h0 = fmaxf(d * (acc.x + sv.x) + b[0], 0.f);
        float h1 = fmaxf(d * (acc.y + sv.y) + b[1], 0.f);
        float h2 = fmaxf(d * (acc.z + sv.z) + b[2], 0.f);
        float h3 = fmaxf(d * (acc.w + sv.w) + b[3], 0.f);
        float o0 = h0 * W[0] + h1 * W[2] + h2 * W[4] + h3 * W[6];
        float o1 = h0 * W[1] + h1 * W[3] + h2 * W[5] + h3 * W[7];
        *(float2*)(dxw_out + (size_t)node * 2) = make_float2(d * o0, d * o1);
    }
}

__global__ __launch_bounds__(TPB) void k_gather2out(
    const unsigned int* __restrict__ indptr, const int* __restrict__ csr_row,
    const float* __restrict__ dinv, const float* __restrict__ dxw3,
    const float* __restrict__ b3, const float* __restrict__ Wc,
    const float* __restrict__ bc,
    float* __restrict__ out, float* __restrict__ y3out, int N) {
    int gid  = blockIdx.x * TPB + threadIdx.x;
    int node = gid >> 4;
    int sub  = gid & 15;
    if (node >= N) return;
    int e0 = (int)indptr[node], e1 = (int)indptr[node + 1];
    float ax = 0.f, ay = 0.f;
    for (int j = e0 + sub; j < e1; j += 16) {
        int r = csr_row[j];
        float2 m = *(const float2*)(dxw3 + (size_t)r * 2);
        ax += m.x; ay += m.y;
    }
#pragma unroll
    for (int off = 1; off < 16; off <<= 1) {
        ax += __shfl_xor(ax, off);
        ay += __shfl_xor(ay, off);
    }
    if (sub == 0) {
        float d = dinv[node];
        float2 sv = *(const float2*)(dxw3 + (size_t)node * 2);
        float y0 = fmaxf(d * (ax + sv.x) + b3[0], 0.f);
        float y1 = fmaxf(d * (ay + sv.y) + b3[1], 0.f);
        float o[4];
#pragma unroll
        for (int j = 0; j < 4; ++j)
            o[j] = y0 * Wc[0 * 4 + j] + y1 * Wc[1 * 4 + j] + bc[j];
        *(float4*)(out + (size_t)node * 4) = make_float4(o[0], o[1], o[2], o[3]);
        *(float2*)(y3out + (size_t)node * 2) = make_float2(y0, y1);
    }
}

// ---------------- R3 fallback kernels (atomic push path) ----------------

__global__ __launch_bounds__(TPB) void k_zero_deg(unsigned int* __restrict__ deg, int N) {
    int i = blockIdx.x * TPB + threadIdx.x;
    if (i < N) deg[i] = 0u;
}

__global__ __launch_bounds__(TPB) void k_deg(
    const int* __restrict__ col, unsigned int* __restrict__ deg, int E) {
    int e = blockIdx.x * TPB + threadIdx.x;
    if (e >= E) return;
    atomicAdd(&deg[col[e]], 1u);
}

__global__ __launch_bounds__(TPB) void k_dinv(const unsigned int* __restrict__ deg,
                                              float* __restrict__ dinv, int N) {
    int i = blockIdx.x * TPB + threadIdx.x;
    if (i < N) dinv[i] = rsqrtf((float)(deg[i] + 1u));
}

__global__ __launch_bounds__(TPB) void k_xw1(
    const float* __restrict__ x, const float* __restrict__ W1,
    const float* __restrict__ dinv,
    float* __restrict__ xw, float* __restrict__ agg, int N) {
    __shared__ float sW[512];
    for (int t = threadIdx.x; t < 512; t += TPB) sW[t] = W1[t];
    __syncthreads();
    int gid  = blockIdx.x * TPB + threadIdx.x;
    int node = gid >> 6;
    int lane = threadIdx.x & 63;
    if (node >= N) return;
    float2 v = *(const float2*)(x + (size_t)node * 128 + 2 * lane);
    const float* w0 = &sW[(2 * lane) * 4];
    const float* w1 = &sW[(2 * lane + 1) * 4];
    float a[4];
#pragma unroll
    for (int j = 0; j < 4; ++j) a[j] = v.x * w0[j] + v.y * w1[j];
#pragma unroll
    for (int off = 32; off > 0; off >>= 1) {
#pragma unroll
        for (int j = 0; j < 4; ++j) a[j] += __shfl_down(a[j], off);
    }
    if (lane == 0) {
        float d  = dinv[node];
        float d2 = d * d;
        *(float4*)(xw  + (size_t)node * 4) = make_float4(a[0], a[1], a[2], a[3]);
        *(float4*)(agg + (size_t)node * 4) =
            make_float4(d2 * a[0], d2 * a[1], d2 * a[2], d2 * a[3]);
    }
}

__global__ __launch_bounds__(TPB) void k_prop4(
    const int* __restrict__ row, const int* __restrict__ col,
    const float* __restrict__ dinv,
    const float* __restrict__ xw, float* __restrict__ agg, int E) {
    int e = blockIdx.x * TPB + threadIdx.x;
    if (e >= E) return;
    int r = row[e];
    int c = col[e];
    float nv = dinv[r] * dinv[c];
    float4 m = *(const float4*)(xw + (size_t)r * 4);
    float* a = agg + (size_t)c * 4;
    atomicAdd(a + 0, nv * m.x);
    atomicAdd(a + 1, nv * m.y);
    atomicAdd(a + 2, nv * m.z);
    atomicAdd(a + 3, nv * m.w);
}

__global__ __launch_bounds__(TPB) void k_prop2(
    const int* __restrict__ row, const int* __restrict__ col,
    const float* __restrict__ dinv,
    const float* __restrict__ xw2, float* __restrict__ agg2, int E) {
    int e = blockIdx.x * TPB + threadIdx.x;
    if (e >= E) return;
    int r = row[e];
    int c = col[e];
    float nv = dinv[r] * dinv[c];
    float2 m = *(const float2*)(xw2 + (size_t)r * 2);
    float* a = agg2 + (size_t)c * 2;
    atomicAdd(a + 0, nv * m.x);
    atomicAdd(a + 1, nv * m.y);
}

__global__ __launch_bounds__(TPB) void k_node2(
    const float* __restrict__ b1, const float* __restrict__ W2,
    const float* __restrict__ dinv,
    float* __restrict__ xw, float* __restrict__ agg, int N) {
    int i = blockIdx.x * TPB + threadIdx.x;
    if (i >= N) return;
    float4 av = *(const float4*)(agg + (size_t)i * 4);
    float h0 = fmaxf(av.x + b1[0], 0.f);
    float h1 = fmaxf(av.y + b1[1], 0.f);
    float h2 = fmaxf(av.z + b1[2], 0.f);
    float h3 = fmaxf(av.w + b1[3], 0.f);
    float o[4];
#pragma unroll
    for (int j = 0; j < 4; ++j)
        o[j] = h0 * W2[0 * 4 + j] + h1 * W2[1 * 4 + j] +
               h2 * W2[2 * 4 + j] + h3 * W2[3 * 4 + j];
    float d  = dinv[i];
    float d2 = d * d;
    *(float4*)(xw  + (size_t)i * 4) = make_float4(o[0], o[1], o[2], o[3]);
    *(float4*)(agg + (size_t)i * 4) = make_float4(d2 * o[0], d2 * o[1], d2 * o[2], d2 * o[3]);
}

__global__ __launch_bounds__(TPB) void k_node3(
    const float* __restrict__ b2, const float* __restrict__ W3,
    const float* __restrict__ dinv,
    const float* __restrict__ agg,
    float* __restrict__ xw3, float* __restrict__ agg3, int N) {
    int i = blockIdx.x * TPB + threadIdx.x;
    if (i >= N) return;
    float4 av = *(const float4*)(agg + (size_t)i * 4);
    float h0 = fmaxf(av.x + b2[0], 0.f);
    float h1 = fmaxf(av.y + b2[1], 0.f);
    float h2 = fmaxf(av.z + b2[2], 0.f);
    float h3 = fmaxf(av.w + b2[3], 0.f);
    float o0 = h0 * W3[0] + h1 * W3[2] + h2 * W3[4] + h3 * W3[6];
    float o1 = h0 * W3[1] + h1 * W3[3] + h2 * W3[5] + h3 * W3[7];
    float d  = dinv[i];
    float d2 = d * d;
    *(float2*)(xw3  + (size_t)i * 2) = make_float2(o0, o1);
    *(float2*)(agg3 + (size_t)i * 2) = make_float2(d2 * o0, d2 * o1);
}

__global__ __launch_bounds__(TPB) void k_out(
    const float* __restrict__ b3, const float* __restrict__ Wc,
    const float* __restrict__ bc,
    const float* __restrict__ agg3,
    float* __restrict__ out, float* __restrict__ y3out, int N) {
    int i = blockIdx.x * TPB + threadIdx.x;
    if (i >= N) return;
    float2 av = *(const float2*)(agg3 + (size_t)i * 2);
    float y0 = fmaxf(av.x + b3[0], 0.f);
    float y1 = fmaxf(av.y + b3[1], 0.f);
    float o[4];
#pragma unroll
    for (int j = 0; j < 4; ++j)
        o[j] = y0 * Wc[0 * 4 + j] + y1 * Wc[1 * 4 + j] + bc[j];
    *(float4*)(out + (size_t)i * 4) = make_float4(o[0], o[1], o[2], o[3]);
    *(float2*)(y3out + (size_t)i * 2) = make_float2(y0, y1);
}

extern "C" void kernel_launch(void* const* d_in, const int* in_sizes, int n_in,
                              void* d_out, int out_size, void* d_ws, size_t ws_size,
                              hipStream_t stream) {
    const float* x  = (const float*)d_in[0];
    const int*   ei = (const int*)d_in[1];   // int32 (harness converts integer inputs)
    const float* W1 = (const float*)d_in[2];
    const float* b1 = (const float*)d_in[3];
    const float* W2 = (const float*)d_in[4];
    const float* b2 = (const float*)d_in[5];
    const float* W3 = (const float*)d_in[6];
    const float* b3 = (const float*)d_in[7];
    const float* Wc = (const float*)d_in[8];
    const float* bc = (const float*)d_in[9];

    const int N = in_sizes[0] / 128;
    const int E = in_sizes[1] / 2;

    const int* row = ei;
    const int* col = ei + (size_t)E;

    const int NB  = (N + SPAN - 1) / SPAN;        // dest buckets (391)
    const int M   = NB * PART_B;                  // flattened hist size (~100K)
    const int PBE = (E + PART_B - 1) / PART_B;    // edges per partition block

    float* out   = (float*)d_out;                  // [N,4]
    float* y3out = (float*)d_out + (size_t)N * 4;  // [N,2]

    const int nblkN = (N + TPB - 1) / TPB;
    const int nblkE = (E + TPB - 1) / TPB;
    const int nblkW = (N * 64 + TPB - 1) / TPB;    // wave-per-node
    const int nblkG = (N * 16 + TPB - 1) / TPB;    // 16 threads/node
    const int nblkM = (M + 1 + TPB - 1) / TPB;
    const int nblkS = (M + SCAN_B - 1) / SCAN_B;   // scan blocks (~25)

    // Fixed carve; bpack gets the remainder (capacity-gated padding).
    size_t off = 0;
    auto carve = [&](size_t bytes) -> void* {
        void* r = (void*)((char*)d_ws + off);
        off += (bytes + 255) & ~(size_t)255;
        return r;
    };
    float*        dinv    = (float*)carve((size_t)N * 4);
    float*        dxw1    = (float*)carve((size_t)N * 4 * 4);
    float*        dxw2    = (float*)carve((size_t)N * 4 * 4);
    float*        dxw3    = (float*)carve((size_t)N * 2 * 4);
    unsigned int* indptr  = (unsigned int*)carve(((size_t)N + 1) * 4);
    uint32_t*     bsumA   = (uint32_t*)carve(260 * 4);
    uint32_t*     bsumB   = (uint32_t*)carve(260 * 4);
    uint32_t*     H       = (uint32_t*)carve((size_t)M * 4);
    uint32_t*     OA      = (uint32_t*)carve(((size_t)M + 1) * 4);
    uint32_t*     OB      = (uint32_t*)carve(((size_t)M + 1) * 4);
    int*          csr_row = (int*)carve((size_t)E * 4);
    // bpack: E words + as much pad budget as ws allows (worst pad = M*31)
    size_t avail_w  = (ws_size > off) ? (ws_size - off) / 4 : 0;
    size_t worst_w  = (size_t)E + (size_t)M * 31u;
    size_t cap_w    = (avail_w < worst_w) ? avail_w : worst_w;
    uint32_t* bpack = (uint32_t*)((char*)d_ws + off);
    off += cap_w * 4;
    bool use_bucket = (cap_w >= (size_t)E) && (NB <= 1024) && (N < (1 << 23));

    if (use_bucket) {
        size_t sort_lds = (size_t)SORT_CAP * 4;  // 72KB dynamic
        hipFuncSetAttribute((const void*)p_sort,
                            hipFuncAttributeMaxDynamicSharedMemorySize,
                            (int)sort_lds);
        p_hist<<<PART_B, PART_T, 0, stream>>>(col, H, NB, E, PBE);
        k_scan1<<<nblkS, SCAN_T, 0, stream>>>(H, OA, bsumA, M, ALIGN_M);  // padded
        k_scan1<<<nblkS, SCAN_T, 0, stream>>>(H, OB, bsumB, M, 0u);       // dense
        k_scan2<<<1, 32, 0, stream>>>(bsumA, nblkS);
        k_scan2<<<1, 32, 0, stream>>>(bsumB, nblkS);
        k_scan3A<<<nblkM, TPB, 0, stream>>>(OA, bsumA, OB, bsumB, M, E,
                                            (unsigned int)cap_w, nblkS);
        k_scan3B<<<nblkM, TPB, 0, stream>>>(OB, bsumB, M, E);
        p_part<<<PART_B, PART_T, 0, stream>>>(row, col, OA, bpack, NB, E, PBE);
        p_sort<<<NB, PART_T, sort_lds, stream>>>(bpack, OA, OB, csr_row, indptr,
                                                 dinv, NB, N, E);
        k_xw1d<<<nblkW, TPB, 0, stream>>>(x, W1, dinv, dxw1, N);
        k_gather44<<<nblkG, TPB, 0, stream>>>(indptr, csr_row, dinv, dxw1, b1, W2, dxw2, N);
        k_gather42<<<nblkG, TPB, 0, stream>>>(indptr, csr_row, dinv, dxw2, b2, W3, dxw3, N);
        k_gather2out<<<nblkG, TPB, 0, stream>>>(indptr, csr_row, dinv, dxw3, b3, Wc, bc,
                                                out, y3out, N);
    } else {
        // R3 verified atomic-push fallback: recarve from base (~6MB).
        size_t foff = 0;
        auto fcarve = [&](size_t bytes) -> void* {
            void* r = (void*)((char*)d_ws + foff);
            foff += (bytes + 255) & ~(size_t)255;
            return r;
        };
        unsigned int* deg   = (unsigned int*)fcarve((size_t)N * 4);
        float*        fdinv = (float*)fcarve((size_t)N * 4);
        float*        xw    = (float*)fcarve((size_t)N * 4 * 4);
        float*        agg   = (float*)fcarve((size_t)N * 4 * 4);
        float*        xw3   = (float*)fcarve((size_t)N * 2 * 4);
        float*        agg3  = (float*)fcarve((size_t)N * 2 * 4);
        k_zero_deg<<<nblkN, TPB, 0, stream>>>(deg, N);
        k_deg<<<nblkE, TPB, 0, stream>>>(col, deg, E);
        k_dinv<<<nblkN, TPB, 0, stream>>>(deg, fdinv, N);
        k_xw1<<<nblkW, TPB, 0, stream>>>(x, W1, fdinv, xw, agg, N);
        k_prop4<<<nblkE, TPB, 0, stream>>>(row, col, fdinv, xw, agg, E);
        k_node2<<<nblkN, TPB, 0, stream>>>(b1, W2, fdinv, xw, agg, N);
        k_prop4<<<nblkE, TPB, 0, stream>>>(row, col, fdinv, xw, agg, E);
        k_node3<<<nblkN, TPB, 0, stream>>>(b2, W3, fdinv, agg, xw3, agg3, N);
        k_prop2<<<nblkE, TPB, 0, stream>>>(row, col, fdinv, xw3, agg3, E);
        k_out<<<nblkN, TPB, 0, stream>>>(b3, Wc, bc, agg3, out, y3out, N);
    }
}

// Round 11
// 223.533 us; speedup vs baseline: 1.0039x; 1.0039x over previous
//
#include <hip/hip_runtime.h>
#include <stdint.h>

#define TPB 256
#define SPAN 256        // nodes per dest bucket (bucket = col>>8)
#define LSH 8           // log2(SPAN)
#define PART_B 256      // partition blocks (one per CU)
#define PART_T 1024     // threads in partition/sort kernels
#define NBMAX 512       // max buckets supported by LDS hist
#define SORT_CAP 18432  // words of dynamic LDS sort buffer (72KB); W ~16384±400

// ---------------------------------------------------------------------------
// GCN 3-layer forward on MI355X.
// R11: block-major bpack. R9/R10: bucket-major bpack forced each block to
// hold ~391 open lines spread over 25.6MB while the 51MB read stream
// thrashed L2 -> 2.6-3x write amp in p_part (69us). Now each block writes
// bucket-grouped edges into its OWN contiguous ~100KB region (offsets from a
// block-LOCAL LDS scan): line-exclusive + 3.2MB/XCD write working set, no
// global scan for placement. p_hist is fused away (two passes over the
// block's col slice); per-(block,bucket) segment table Pg (0.4MB) + one
// 391-wide scan of bucket totals drive p_sort, which reads the 256 segments
// of its bucket (wave-per-segment), LDS counting-sorts, writes csr
// coalesced, and emits indptr+dinv. Gathers unchanged.
// agg[c] = dinv[c]*(sum_in dxw[r] + dxw[c]), dxw = dinv*(h@W).
// WS ~57MB (proven budget). R3 atomic-push fallback kept.
// ---------------------------------------------------------------------------

__global__ __launch_bounds__(256) void k_zero32(uint32_t* __restrict__ p, int n) {
    int i = blockIdx.x * 256 + threadIdx.x;
    if (i < n) p[i] = 0u;
}

// Fused hist+partition, block-major output.
// Block blk owns edge slice [blk*PBE, min(E,(blk+1)*PBE)):
//   pass1: LDS bucket histogram of its slice
//   local exclusive scan -> Pg[blk][b] (segment offsets within its region)
//   global Hb[b] += hist[b] (per-bucket totals, 391 atomics/block)
//   pass2: scatter (row<<LSH)|ldest into its own region at blk*PBE+P[b]+rank
__global__ __launch_bounds__(PART_T) void p_part(
    const int* __restrict__ row, const int* __restrict__ col,
    uint32_t* __restrict__ bpack, uint32_t* __restrict__ Pg,
    uint32_t* __restrict__ Hb, int NB, int E, int PBE) {
    __shared__ uint32_t hist[NBMAX];
    __shared__ uint32_t cur[NBMAX];
    int blk = blockIdx.x;
    int t   = threadIdx.x;
    int s = blk * PBE, e = min(E, s + PBE);
    int len = e - s;
    for (int i = t; i < NB; i += PART_T) hist[i] = 0u;
    __syncthreads();
    for (int i = s + t; i < e; i += PART_T)
        atomicAdd(&hist[col[i] >> LSH], 1u);
    __syncthreads();
    if (t < NB) cur[t] = hist[t];
    __syncthreads();
    for (int off = 1; off < NB; off <<= 1) {  // Hillis-Steele inclusive
        uint32_t v = (t < NB && t >= off) ? cur[t - off] : 0u;
        __syncthreads();
        if (t < NB) cur[t] += v;
        __syncthreads();
    }
    if (t < NB) {
        uint32_t excl = cur[t] - hist[t];
        Pg[(size_t)blk * (NB + 1) + t] = excl;
        if (hist[t]) atomicAdd(&Hb[t], hist[t]);
        cur[t] = (uint32_t)s + excl;  // global cursor in own region
    }
    if (t == 0) Pg[(size_t)blk * (NB + 1) + NB] = (uint32_t)len;
    __syncthreads();
    for (int i = s + t; i < e; i += PART_T) {
        int c = col[i];
        uint32_t slot = atomicAdd(&cur[c >> LSH], 1u);
        bpack[slot] = ((uint32_t)row[i] << LSH) | (uint32_t)(c & (SPAN - 1));
    }
}

// Single-block exclusive scan of bucket totals Hb[0..NB) -> Ob; Ob[NB]=E.
__global__ __launch_bounds__(NBMAX) void k_scanb(
    const uint32_t* __restrict__ Hb, uint32_t* __restrict__ Ob, int NB, int E) {
    __shared__ uint32_t sm[NBMAX];
    int t = threadIdx.x;
    uint32_t v = (t < NB) ? Hb[t] : 0u;
    sm[t] = v;
    __syncthreads();
    for (int off = 1; off < NBMAX; off <<= 1) {
        uint32_t u = (t >= off) ? sm[t - off] : 0u;
        __syncthreads();
        sm[t] += u;
        __syncthreads();
    }
    if (t < NB) Ob[t] = sm[t] - v;
    if (t == 0) Ob[NB] = (uint32_t)E;
}

// Per-bucket counting sort. Bucket b's edges live in 256 segments
// (one per partition block, located via Pg). Wave-per-segment reads,
// LDS staging, coalesced csr writeout. Emits indptr + dinv.
extern __shared__ uint32_t sort_buf[];
__global__ __launch_bounds__(PART_T) void p_sort(
    const uint32_t* __restrict__ bpack, const uint32_t* __restrict__ Pg,
    const uint32_t* __restrict__ Ob,
    int* __restrict__ csr_row, unsigned int* __restrict__ indptr,
    float* __restrict__ dinv, int NB, int N, int E, int PBE) {
    __shared__ uint32_t hist[SPAN];
    __shared__ uint32_t cur[SPAN];
    int b = blockIdx.x;
    int t = threadIdx.x;
    int wid  = t >> 6;          // 16 waves
    int lane = t & 63;
    if (t < SPAN) hist[t] = 0u;
    __syncthreads();
    uint32_t ub = Ob[b], ue = Ob[b + 1];
    uint32_t W = ue - ub;
    for (int blk = wid; blk < PART_B; blk += (PART_T >> 6)) {
        const uint32_t* pb = Pg + (size_t)blk * (NB + 1);
        uint32_t o0 = pb[b], o1 = pb[b + 1];
        uint32_t base = (uint32_t)(blk * PBE) + o0;
        uint32_t L = o1 - o0;
        for (uint32_t j = lane; j < L; j += 64)
            atomicAdd(&hist[bpack[base + j] & (SPAN - 1)], 1u);
    }
    __syncthreads();
    if (t < SPAN) cur[t] = hist[t];
    __syncthreads();
    for (int off = 1; off < SPAN; off <<= 1) {  // Hillis-Steele inclusive
        uint32_t v = (t < SPAN && t >= off) ? cur[t - off] : 0u;
        __syncthreads();
        if (t < SPAN) cur[t] += v;
        __syncthreads();
    }
    if (t < SPAN) {
        uint32_t excl = cur[t] - hist[t];
        int n = b * SPAN + t;
        if (n < N) {
            indptr[n] = ub + excl;
            dinv[n]   = rsqrtf((float)(hist[t] + 1u));  // +1 = self loop
            if (n == N - 1) indptr[N] = (unsigned int)E;
        }
        cur[t] = excl;  // window-local cursor
    }
    __syncthreads();
    if (W <= SORT_CAP) {
        for (int blk = wid; blk < PART_B; blk += (PART_T >> 6)) {
            const uint32_t* pb = Pg + (size_t)blk * (NB + 1);
            uint32_t o0 = pb[b], o1 = pb[b + 1];
            uint32_t base = (uint32_t)(blk * PBE) + o0;
            uint32_t L = o1 - o0;
            for (uint32_t j = lane; j < L; j += 64) {
                uint32_t v = bpack[base + j];
                uint32_t slot = atomicAdd(&cur[v & (SPAN - 1)], 1u);
                sort_buf[slot] = v >> LSH;
            }
        }
        __syncthreads();
        for (uint32_t j = t; j < W; j += PART_T)
            csr_row[ub + j] = (int)sort_buf[j];
    } else {
        for (int blk = wid; blk < PART_B; blk += (PART_T >> 6)) {
            const uint32_t* pb = Pg + (size_t)blk * (NB + 1);
            uint32_t o0 = pb[b], o1 = pb[b + 1];
            uint32_t base = (uint32_t)(blk * PBE) + o0;
            uint32_t L = o1 - o0;
            for (uint32_t j = lane; j < L; j += 64) {
                uint32_t v = bpack[base + j];
                uint32_t slot = atomicAdd(&cur[v & (SPAN - 1)], 1u);
                csr_row[ub + slot] = (int)(v >> LSH);
            }
        }
    }
}

// ---------------- node / gather kernels (main path) ----------------

__global__ __launch_bounds__(TPB) void k_xw1d(
    const float* __restrict__ x, const float* __restrict__ W1,
    const float* __restrict__ dinv, float* __restrict__ dxw1, int N) {
    __shared__ float sW[512];  // 128 x 4
    for (int t = threadIdx.x; t < 512; t += TPB) sW[t] = W1[t];
    __syncthreads();
    int gid  = blockIdx.x * TPB + threadIdx.x;
    int node = gid >> 6;
    int lane = threadIdx.x & 63;
    if (node >= N) return;
    float2 v = *(const float2*)(x + (size_t)node * 128 + 2 * lane);
    const float* w0 = &sW[(2 * lane) * 4];
    const float* w1 = &sW[(2 * lane + 1) * 4];
    float a[4];
#pragma unroll
    for (int j = 0; j < 4; ++j) a[j] = v.x * w0[j] + v.y * w1[j];
#pragma unroll
    for (int off = 32; off > 0; off >>= 1) {
#pragma unroll
        for (int j = 0; j < 4; ++j) a[j] += __shfl_down(a[j], off);
    }
    if (lane == 0) {
        float d = dinv[node];
        *(float4*)(dxw1 + (size_t)node * 4) =
            make_float4(d * a[0], d * a[1], d * a[2], d * a[3]);
    }
}

__global__ __launch_bounds__(TPB) void k_gather44(
    const unsigned int* __restrict__ indptr, const int* __restrict__ csr_row,
    const float* __restrict__ dinv, const float* __restrict__ dxw_in,
    const float* __restrict__ b, const float* __restrict__ W,
    float* __restrict__ dxw_out, int N) {
    int gid  = blockIdx.x * TPB + threadIdx.x;
    int node = gid >> 4;
    int sub  = gid & 15;
    if (node >= N) return;
    int e0 = (int)indptr[node], e1 = (int)indptr[node + 1];
    float4 acc = make_float4(0.f, 0.f, 0.f, 0.f);
    for (int j = e0 + sub; j < e1; j += 16) {
        int r = csr_row[j];
        float4 m = *(const float4*)(dxw_in + (size_t)r * 4);
        acc.x += m.x; acc.y += m.y; acc.z += m.z; acc.w += m.w;
    }
#pragma unroll
    for (int off = 1; off < 16; off <<= 1) {
        acc.x += __shfl_xor(acc.x, off);
        acc.y += __shfl_xor(acc.y, off);
        acc.z += __shfl_xor(acc.z, off);
        acc.w += __shfl_xor(acc.w, off);
    }
    if (sub == 0) {
        float d = dinv[node];
        float4 sv = *(const float4*)(dxw_in + (size_t)node * 4);
        float h0 = fmaxf(d * (acc.x + sv.x) + b[0], 0.f);
        float h1 = fmaxf(d * (acc.y + sv.y) + b[1], 0.f);
        float h2 = fmaxf(d * (acc.z + sv.z) + b[2], 0.f);
        float h3 = fmaxf(d * (acc.w + sv.w) + b[3], 0.f);
        float o[4];
#pragma unroll
        for (int j = 0; j < 4; ++j)
            o[j] = h0 * W[0 * 4 + j] + h1 * W[1 * 4 + j] +
                   h2 * W[2 * 4 + j] + h3 * W[3 * 4 + j];
        *(float4*)(dxw_out + (size_t)node * 4) =
            make_float4(d * o[0], d * o[1], d * o[2], d * o[3]);
    }
}

__global__ __launch_bounds__(TPB) void k_gather42(
    const unsigned int* __restrict__ indptr, const int* __restrict__ csr_row,
    const float* __restrict__ dinv, const float* __restrict__ dxw_in,
    const float* __restrict__ b, const float* __restrict__ W,
    float* __restrict__ dxw_out, int N) {
    int gid  = blockIdx.x * TPB + threadIdx.x;
    int node = gid >> 4;
    int sub  = gid & 15;
    if (node >= N) return;
    int e0 = (int)indptr[node], e1 = (int)indptr[node + 1];
    float4 acc = make_float4(0.f, 0.f, 0.f, 0.f);
    for (int j = e0 + sub; j < e1; j += 16) {
        int r = csr_row[j];
        float4 m = *(const float4*)(dxw_in + (size_t)r * 4);
        acc.x += m.x; acc.y += m.y; acc.z += m.z; acc.w += m.w;
    }
#pragma unroll
    for (int off = 1; off < 16; off <<= 1) {
        acc.x += __shfl_xor(acc.x, off);
        acc.y += __shfl_xor(acc.y, off);
        acc.z += __shfl_xor(acc.z, off);
        acc.w += __shfl_xor(acc.w, off);
    }
    if (sub == 0) {
        float d = dinv[node];
        float4 sv = *(const float4*)(dxw_in + (size_t)node * 4);
        float h0 = fmaxf(d * (acc.x + sv.x) + b[0], 0.f);
        float h1 = fmaxf(d * (acc.y + sv.y) + b[1], 0.f);
        float h2 = fmaxf(d * (acc.z + sv.z) + b[2], 0.f);
        float h3 = fmaxf(d * (acc.w + sv.w) + b[3], 0.f);
        float o0 = h0 * W[0] + h1 * W[2] + h2 * W[4] + h3 * W[6];
        float o1 = h0 * W[1] + h1 * W[3] + h2 * W[5] + h3 * W[7];
        *(float2*)(dxw_out + (size_t)node * 2) = make_float2(d * o0, d * o1);
    }
}

__global__ __launch_bounds__(TPB) void k_gather2out(
    const unsigned int* __restrict__ indptr, const int* __restrict__ csr_row,
    const float* __restrict__ dinv, const float* __restrict__ dxw3,
    const float* __restrict__ b3, const float* __restrict__ Wc,
    const float* __restrict__ bc,
    float* __restrict__ out, float* __restrict__ y3out, int N) {
    int gid  = blockIdx.x * TPB + threadIdx.x;
    int node = gid >> 4;
    int sub  = gid & 15;
    if (node >= N) return;
    int e0 = (int)indptr[node], e1 = (int)indptr[node + 1];
    float ax = 0.f, ay = 0.f;
    for (int j = e0 + sub; j < e1; j += 16) {
        int r = csr_row[j];
        float2 m = *(const float2*)(dxw3 + (size_t)r * 2);
        ax += m.x; ay += m.y;
    }
#pragma unroll
    for (int off = 1; off < 16; off <<= 1) {
        ax += __shfl_xor(ax, off);
        ay += __shfl_xor(ay, off);
    }
    if (sub == 0) {
        float d = dinv[node];
        float2 sv = *(const float2*)(dxw3 + (size_t)node * 2);
        float y0 = fmaxf(d * (ax + sv.x) + b3[0], 0.f);
        float y1 = fmaxf(d * (ay + sv.y) + b3[1], 0.f);
        float o[4];
#pragma unroll
        for (int j = 0; j < 4; ++j)
            o[j] = y0 * Wc[0 * 4 + j] + y1 * Wc[1 * 4 + j] + bc[j];
        *(float4*)(out + (size_t)node * 4) = make_float4(o[0], o[1], o[2], o[3]);
        *(float2*)(y3out + (size_t)node * 2) = make_float2(y0, y1);
    }
}

// ---------------- R3 fallback kernels (atomic push path) ----------------

__global__ __launch_bounds__(TPB) void k_zero_deg(unsigned int* __restrict__ deg, int N) {
    int i = blockIdx.x * TPB + threadIdx.x;
    if (i < N) deg[i] = 0u;
}

__global__ __launch_bounds__(TPB) void k_deg(
    const int* __restrict__ col, unsigned int* __restrict__ deg, int E) {
    int e = blockIdx.x * TPB + threadIdx.x;
    if (e >= E) return;
    atomicAdd(&deg[col[e]], 1u);
}

__global__ __launch_bounds__(TPB) void k_dinv(const unsigned int* __restrict__ deg,
                                              float* __restrict__ dinv, int N) {
    int i = blockIdx.x * TPB + threadIdx.x;
    if (i < N) dinv[i] = rsqrtf((float)(deg[i] + 1u));
}

__global__ __launch_bounds__(TPB) void k_xw1(
    const float* __restrict__ x, const float* __restrict__ W1,
    const float* __restrict__ dinv,
    float* __restrict__ xw, float* __restrict__ agg, int N) {
    __shared__ float sW[512];
    for (int t = threadIdx.x; t < 512; t += TPB) sW[t] = W1[t];
    __syncthreads();
    int gid  = blockIdx.x * TPB + threadIdx.x;
    int node = gid >> 6;
    int lane = threadIdx.x & 63;
    if (node >= N) return;
    float2 v = *(const float2*)(x + (size_t)node * 128 + 2 * lane);
    const float* w0 = &sW[(2 * lane) * 4];
    const float* w1 = &sW[(2 * lane + 1) * 4];
    float a[4];
#pragma unroll
    for (int j = 0; j < 4; ++j) a[j] = v.x * w0[j] + v.y * w1[j];
#pragma unroll
    for (int off = 32; off > 0; off >>= 1) {
#pragma unroll
        for (int j = 0; j < 4; ++j) a[j] += __shfl_down(a[j], off);
    }
    if (lane == 0) {
        float d  = dinv[node];
        float d2 = d * d;
        *(float4*)(xw  + (size_t)node * 4) = make_float4(a[0], a[1], a[2], a[3]);
        *(float4*)(agg + (size_t)node * 4) =
            make_float4(d2 * a[0], d2 * a[1], d2 * a[2], d2 * a[3]);
    }
}

__global__ __launch_bounds__(TPB) void k_prop4(
    const int* __restrict__ row, const int* __restrict__ col,
    const float* __restrict__ dinv,
    const float* __restrict__ xw, float* __restrict__ agg, int E) {
    int e = blockIdx.x * TPB + threadIdx.x;
    if (e >= E) return;
    int r = row[e];
    int c = col[e];
    float nv = dinv[r] * dinv[c];
    float4 m = *(const float4*)(xw + (size_t)r * 4);
    float* a = agg + (size_t)c * 4;
    atomicAdd(a + 0, nv * m.x);
    atomicAdd(a + 1, nv * m.y);
    atomicAdd(a + 2, nv * m.z);
    atomicAdd(a + 3, nv * m.w);
}

__global__ __launch_bounds__(TPB) void k_prop2(
    const int* __restrict__ row, const int* __restrict__ col,
    const float* __restrict__ dinv,
    const float* __restrict__ xw2, float* __restrict__ agg2, int E) {
    int e = blockIdx.x * TPB + threadIdx.x;
    if (e >= E) return;
    int r = row[e];
    int c = col[e];
    float nv = dinv[r] * dinv[c];
    float2 m = *(const float2*)(xw2 + (size_t)r * 2);
    float* a = agg2 + (size_t)c * 2;
    atomicAdd(a + 0, nv * m.x);
    atomicAdd(a + 1, nv * m.y);
}

__global__ __launch_bounds__(TPB) void k_node2(
    const float* __restrict__ b1, const float* __restrict__ W2,
    const float* __restrict__ dinv,
    float* __restrict__ xw, float* __restrict__ agg, int N) {
    int i = blockIdx.x * TPB + threadIdx.x;
    if (i >= N) return;
    float4 av = *(const float4*)(agg + (size_t)i * 4);
    float h0 = fmaxf(av.x + b1[0], 0.f);
    float h1 = fmaxf(av.y + b1[1], 0.f);
    float h2 = fmaxf(av.z + b1[2], 0.f);
    float h3 = fmaxf(av.w + b1[3], 0.f);
    float o[4];
#pragma unroll
    for (int j = 0; j < 4; ++j)
        o[j] = h0 * W2[0 * 4 + j] + h1 * W2[1 * 4 + j] +
               h2 * W2[2 * 4 + j] + h3 * W2[3 * 4 + j];
    float d  = dinv[i];
    float d2 = d * d;
    *(float4*)(xw  + (size_t)i * 4) = make_float4(o[0], o[1], o[2], o[3]);
    *(float4*)(agg + (size_t)i * 4) = make_float4(d2 * o[0], d2 * o[1], d2 * o[2], d2 * o[3]);
}

__global__ __launch_bounds__(TPB) void k_node3(
    const float* __restrict__ b2, const float* __restrict__ W3,
    const float* __restrict__ dinv,
    const float* __restrict__ agg,
    float* __restrict__ xw3, float* __restrict__ agg3, int N) {
    int i = blockIdx.x * TPB + threadIdx.x;
    if (i >= N) return;
    float4 av = *(const float4*)(agg + (size_t)i * 4);
    float h0 = fmaxf(av.x + b2[0], 0.f);
    float h1 = fmaxf(av.y + b2[1], 0.f);
    float h2 = fmaxf(av.z + b2[2], 0.f);
    float h3 = fmaxf(av.w + b2[3], 0.f);
    float o0 = h0 * W3[0] + h1 * W3[2] + h2 * W3[4] + h3 * W3[6];
    float o1 = h0 * W3[1] + h1 * W3[3] + h2 * W3[5] + h3 * W3[7];
    float d  = dinv[i];
    float d2 = d * d;
    *(float2*)(xw3  + (size_t)i * 2) = make_float2(o0, o1);
    *(float2*)(agg3 + (size_t)i * 2) = make_float2(d2 * o0, d2 * o1);
}

__global__ __launch_bounds__(TPB) void k_out(
    const float* __restrict__ b3, const float* __restrict__ Wc,
    const float* __restrict__ bc,
    const float* __restrict__ agg3,
    float* __restrict__ out, float* __restrict__ y3out, int N) {
    int i = blockIdx.x * TPB + threadIdx.x;
    if (i >= N) return;
    float2 av = *(const float2*)(agg3 + (size_t)i * 2);
    float y0 = fmaxf(av.x + b3[0], 0.f);
    float y1 = fmaxf(av.y + b3[1], 0.f);
    float o[4];
#pragma unroll
    for (int j = 0; j < 4; ++j)
        o[j] = y0 * Wc[0 * 4 + j] + y1 * Wc[1 * 4 + j] + bc[j];
    *(float4*)(out + (size_t)i * 4) = make_float4(o[0], o[1], o[2], o[3]);
    *(float2*)(y3out + (size_t)i * 2) = make_float2(y0, y1);
}

extern "C" void kernel_launch(void* const* d_in, const int* in_sizes, int n_in,
                              void* d_out, int out_size, void* d_ws, size_t ws_size,
                              hipStream_t stream) {
    const float* x  = (const float*)d_in[0];
    const int*   ei = (const int*)d_in[1];   // int32 (harness converts integer inputs)
    const float* W1 = (const float*)d_in[2];
    const float* b1 = (const float*)d_in[3];
    const float* W2 = (const float*)d_in[4];
    const float* b2 = (const float*)d_in[5];
    const float* W3 = (const float*)d_in[6];
    const float* b3 = (const float*)d_in[7];
    const float* Wc = (const float*)d_in[8];
    const float* bc = (const float*)d_in[9];

    const int N = in_sizes[0] / 128;
    const int E = in_sizes[1] / 2;

    const int* row = ei;
    const int* col = ei + (size_t)E;

    const int NB  = (N + SPAN - 1) / SPAN;        // dest buckets (391)
    const int PBE = (E + PART_B - 1) / PART_B;    // edges per partition block

    float* out   = (float*)d_out;                  // [N,4]
    float* y3out = (float*)d_out + (size_t)N * 4;  // [N,2]

    const int nblkW = (N * 64 + TPB - 1) / TPB;    // wave-per-node
    const int nblkG = (N * 16 + TPB - 1) / TPB;    // 16 threads/node
    const int nblkN = (N + TPB - 1) / TPB;
    const int nblkE = (E + TPB - 1) / TPB;

    // Carve (~57MB total).
    size_t off = 0;
    auto carve = [&](size_t bytes) -> void* {
        void* r = (void*)((char*)d_ws + off);
        off += (bytes + 255) & ~(size_t)255;
        return r;
    };
    float*        dinv    = (float*)carve((size_t)N * 4);
    float*        dxw1    = (float*)carve((size_t)N * 4 * 4);
    float*        dxw2    = (float*)carve((size_t)N * 4 * 4);
    float*        dxw3    = (float*)carve((size_t)N * 2 * 4);
    unsigned int* indptr  = (unsigned int*)carve(((size_t)N + 1) * 4);
    uint32_t*     Hb      = (uint32_t*)carve((size_t)(NB + 1) * 4);
    uint32_t*     Ob      = (uint32_t*)carve((size_t)(NB + 1) * 4);
    uint32_t*     Pg      = (uint32_t*)carve((size_t)PART_B * (NB + 1) * 4);  // 0.4MB
    uint32_t*     bpack   = (uint32_t*)carve((size_t)PART_B * PBE * 4);       // ~25.6MB
    int*          csr_row = (int*)carve((size_t)E * 4);                       // 25.6MB
    bool use_bucket = (off <= ws_size) && (NB <= NBMAX) && (N < (1 << 24));

    if (use_bucket) {
        size_t sort_lds = (size_t)SORT_CAP * 4;  // 72KB dynamic
        hipFuncSetAttribute((const void*)p_sort,
                            hipFuncAttributeMaxDynamicSharedMemorySize,
                            (int)sort_lds);
        k_zero32<<<(NB + 256) / 256, 256, 0, stream>>>(Hb, NB + 1);
        p_part<<<PART_B, PART_T, 0, stream>>>(row, col, bpack, Pg, Hb, NB, E, PBE);
        k_scanb<<<1, NBMAX, 0, stream>>>(Hb, Ob, NB, E);
        p_sort<<<NB, PART_T, sort_lds, stream>>>(bpack, Pg, Ob, csr_row, indptr,
                                                 dinv, NB, N, E, PBE);
        k_xw1d<<<nblkW, TPB, 0, stream>>>(x, W1, dinv, dxw1, N);
        k_gather44<<<nblkG, TPB, 0, stream>>>(indptr, csr_row, dinv, dxw1, b1, W2, dxw2, N);
        k_gather42<<<nblkG, TPB, 0, stream>>>(indptr, csr_row, dinv, dxw2, b2, W3, dxw3, N);
        k_gather2out<<<nblkG, TPB, 0, stream>>>(indptr, csr_row, dinv, dxw3, b3, Wc, bc,
                                                out, y3out, N);
    } else {
        // R3 verified atomic-push fallback: recarve from base (~6MB).
        size_t foff = 0;
        auto fcarve = [&](size_t bytes) -> void* {
            void* r = (void*)((char*)d_ws + foff);
            foff += (bytes + 255) & ~(size_t)255;
            return r;
        };
        unsigned int* deg   = (unsigned int*)fcarve((size_t)N * 4);
        float*        fdinv = (float*)fcarve((size_t)N * 4);
        float*        xw    = (float*)fcarve((size_t)N * 4 * 4);
        float*        agg   = (float*)fcarve((size_t)N * 4 * 4);
        float*        xw3   = (float*)fcarve((size_t)N * 2 * 4);
        float*        agg3  = (float*)fcarve((size_t)N * 2 * 4);
        k_zero_deg<<<nblkN, TPB, 0, stream>>>(deg, N);
        k_deg<<<nblkE, TPB, 0, stream>>>(col, deg, E);
        k_dinv<<<nblkN, TPB, 0, stream>>>(deg, fdinv, N);
        k_xw1<<<nblkW, TPB, 0, stream>>>(x, W1, fdinv, xw, agg, N);
        k_prop4<<<nblkE, TPB, 0, stream>>>(row, col, fdinv, xw, agg, E);
        k_node2<<<nblkN, TPB, 0, stream>>>(b1, W2, fdinv, xw, agg, N);
        k_prop4<<<nblkE, TPB, 0, stream>>>(row, col, fdinv, xw, agg, E);
        k_node3<<<nblkN, TPB, 0, stream>>>(b2, W3, fdinv, agg, xw3, agg3, N);
        k_prop2<<<nblkE, TPB, 0, stream>>>(row, col, fdinv, xw3, agg3, E);
        k_out<<<nblkN, TPB, 0, stream>>>(b3, Wc, bc, agg3, out, y3out, N);
    }
}

// Round 12
// 208.626 us; speedup vs baseline: 1.0756x; 1.0715x over previous
//
#include <hip/hip_runtime.h>
#include <stdint.h>

#define TPB 256
#define SPAN 512        // nodes per dest bucket (bucket = col>>9)
#define LSH 9           // log2(SPAN)
#define PART_B 256      // partition blocks (one per CU)
#define PART_T 1024     // threads in hist/partition/sort kernels
#define SCAN_T 1024
#define SCAN_B 4096     // elements per scan block (1024 thr x 4)
#define SORT_CAP 35840  // words of dynamic LDS sort buffer (140KB); W ~32653±180

// ---------------------------------------------------------------------------
// GCN 3-layer forward on MI355X.
// R12: combine the two proven p_part facts: R8 (512B runs -> amp 1.1, WRITE
// 29MB) + R9 (256 blocks -> full occupancy). SPAN 256->512 with PART_B=256
// gives 128-word (512B) runs at one block per CU. p_sort becomes one block
// per 512-bucket (grid 196) with a 140KB dynamic-LDS staging buffer (+4KB
// hist/cur = 144KB <= 160KB/CU), same LDS counting-sort + coalesced csr
// writeout as R9. Dense layout = ONE scan chain: bpack window base == csr
// window base, indptr[n] = base + excl (R10's dual-scan machinery deleted).
// Pipeline: p_hist | scan(in place) | p_part | p_sort | xw1d | 3x CSR gather.
// agg[c] = dinv[c]*(sum_in dxw[r] + dxw[c]), dxw = dinv*(h@W).
// WS ~56.2MB. R3 atomic-push fallback kept.
// ---------------------------------------------------------------------------

// ---------------- bucket partition ----------------

__global__ __launch_bounds__(PART_T) void p_hist(
    const int* __restrict__ col, uint32_t* __restrict__ H,
    int NB, int E, int PBE) {
    __shared__ uint32_t cnt[1024];
    for (int i = threadIdx.x; i < NB; i += PART_T) cnt[i] = 0u;
    __syncthreads();
    int blk = blockIdx.x;
    int s = blk * PBE, e = min(E, s + PBE);
    for (int i = s + threadIdx.x; i < e; i += PART_T)
        atomicAdd(&cnt[col[i] >> LSH], 1u);
    __syncthreads();
    for (int i = threadIdx.x; i < NB; i += PART_T)
        H[(size_t)i * PART_B + blk] = cnt[i];
}

// Scan phase 1 (in-place safe: reads then writes same indices).
__global__ __launch_bounds__(SCAN_T) void k_scan1(
    const unsigned int* __restrict__ in, unsigned int* __restrict__ partial,
    unsigned int* __restrict__ bsum, int M) {
    __shared__ unsigned int sm[SCAN_T];
    int tid  = threadIdx.x;
    int base = blockIdx.x * SCAN_B + tid * 4;
    unsigned int v0 = (base + 0 < M) ? in[base + 0] : 0u;
    unsigned int v1 = (base + 1 < M) ? in[base + 1] : 0u;
    unsigned int v2 = (base + 2 < M) ? in[base + 2] : 0u;
    unsigned int v3 = (base + 3 < M) ? in[base + 3] : 0u;
    unsigned int s = v0 + v1 + v2 + v3;
    sm[tid] = s;
    __syncthreads();
    for (int off = 1; off < SCAN_T; off <<= 1) {
        unsigned int t = (tid >= off) ? sm[tid - off] : 0u;
        __syncthreads();
        sm[tid] += t;
        __syncthreads();
    }
    unsigned int excl = sm[tid] - s;
    if (base + 0 < M) partial[base + 0] = excl;
    if (base + 1 < M) partial[base + 1] = excl + v0;
    if (base + 2 < M) partial[base + 2] = excl + v0 + v1;
    if (base + 3 < M) partial[base + 3] = excl + v0 + v1 + v2;
    if (tid == SCAN_T - 1) bsum[blockIdx.x] = sm[SCAN_T - 1];
}

__global__ void k_scan2(unsigned int* __restrict__ bsum, int nb) {
    if (threadIdx.x == 0 && blockIdx.x == 0) {
        unsigned int run = 0;
        for (int i = 0; i < nb; ++i) {
            unsigned int t = bsum[i];
            bsum[i] = run;
            run += t;
        }
    }
}

// Scan phase 3 (in-place safe: outp may alias partial).
__global__ __launch_bounds__(TPB) void k_scan3(
    const unsigned int* __restrict__ partial, const unsigned int* __restrict__ bsum,
    unsigned int* __restrict__ outp, int M, int E) {
    int i = blockIdx.x * TPB + threadIdx.x;
    if (i < M) outp[i] = partial[i] + bsum[i / SCAN_B];
    if (i == 0) outp[M] = (unsigned int)E;
}

// Partition: write bpack[slot] = (row<<LSH)|ldest, bucket-grouped.
// 512B average runs per (bucket,block) segment.
__global__ __launch_bounds__(PART_T) void p_part(
    const int* __restrict__ row, const int* __restrict__ col,
    const uint32_t* __restrict__ O, uint32_t* __restrict__ bpack,
    int NB, int E, int PBE) {
    __shared__ uint32_t cur[1024];
    int blk = blockIdx.x;
    for (int i = threadIdx.x; i < NB; i += PART_T)
        cur[i] = O[(size_t)i * PART_B + blk];
    __syncthreads();
    int s = blk * PBE, e = min(E, s + PBE);
    for (int i = s + threadIdx.x; i < e; i += PART_T) {
        int c = col[i];
        uint32_t slot = atomicAdd(&cur[c >> LSH], 1u);
        bpack[slot] = ((uint32_t)row[i] << LSH) | (uint32_t)(c & (SPAN - 1));
    }
}

// Per-bucket counting sort (512-node buckets): LDS staging (140KB dynamic),
// coalesced csr writeout. Emits indptr + dinv. Fallback to direct stores if
// window > SORT_CAP (prob ~1e-60 for uniform random edges).
extern __shared__ uint32_t sort_buf[];
__global__ __launch_bounds__(PART_T) void p_sort(
    const uint32_t* __restrict__ bpack, const uint32_t* __restrict__ O,
    int* __restrict__ csr_row, unsigned int* __restrict__ indptr,
    float* __restrict__ dinv, int NB, int N, int E) {
    __shared__ uint32_t hist[SPAN];
    __shared__ uint32_t cur[SPAN];
    int b = blockIdx.x;
    int t = threadIdx.x;
    if (t < SPAN) hist[t] = 0u;
    __syncthreads();
    uint32_t s = O[(size_t)b * PART_B];
    uint32_t e = O[(size_t)(b + 1) * PART_B];  // b+1==NB -> O[M]==E sentinel
    uint32_t W = e - s;
    for (uint32_t i = s + t; i < e; i += PART_T)
        atomicAdd(&hist[bpack[i] & (SPAN - 1)], 1u);
    __syncthreads();
    if (t < SPAN) cur[t] = hist[t];
    __syncthreads();
    for (int off = 1; off < SPAN; off <<= 1) {  // Hillis-Steele inclusive scan
        uint32_t v = (t < SPAN && t >= off) ? cur[t - off] : 0u;
        __syncthreads();
        if (t < SPAN) cur[t] += v;
        __syncthreads();
    }
    if (t < SPAN) {
        uint32_t excl = cur[t] - hist[t];
        int n = b * SPAN + t;
        if (n < N) {
            indptr[n] = s + excl;                      // dense: csr base == bpack base
            dinv[n]   = rsqrtf((float)(hist[t] + 1u)); // +1 = self loop
            if (n == N - 1) indptr[N] = (unsigned int)E;
        }
        cur[t] = excl;  // window-local cursor
    }
    __syncthreads();
    if (W <= SORT_CAP) {
        for (uint32_t i = s + t; i < e; i += PART_T) {
            uint32_t v = bpack[i];
            uint32_t slot = atomicAdd(&cur[v & (SPAN - 1)], 1u);
            sort_buf[slot] = v >> LSH;
        }
        __syncthreads();
        for (uint32_t j = t; j < W; j += PART_T)
            csr_row[s + j] = (int)sort_buf[j];
    } else {
        for (uint32_t i = s + t; i < e; i += PART_T) {
            uint32_t v = bpack[i];
            uint32_t slot = atomicAdd(&cur[v & (SPAN - 1)], 1u);
            csr_row[s + slot] = (int)(v >> LSH);
        }
    }
}

// ---------------- node / gather kernels (main path) ----------------

// dxw1 = dinv * (x @ W1), wave per node.
__global__ __launch_bounds__(TPB) void k_xw1d(
    const float* __restrict__ x, const float* __restrict__ W1,
    const float* __restrict__ dinv, float* __restrict__ dxw1, int N) {
    __shared__ float sW[512];  // 128 x 4
    for (int t = threadIdx.x; t < 512; t += TPB) sW[t] = W1[t];
    __syncthreads();
    int gid  = blockIdx.x * TPB + threadIdx.x;
    int node = gid >> 6;
    int lane = threadIdx.x & 63;
    if (node >= N) return;
    float2 v = *(const float2*)(x + (size_t)node * 128 + 2 * lane);
    const float* w0 = &sW[(2 * lane) * 4];
    const float* w1 = &sW[(2 * lane + 1) * 4];
    float a[4];
#pragma unroll
    for (int j = 0; j < 4; ++j) a[j] = v.x * w0[j] + v.y * w1[j];
#pragma unroll
    for (int off = 32; off > 0; off >>= 1) {
#pragma unroll
        for (int j = 0; j < 4; ++j) a[j] += __shfl_down(a[j], off);
    }
    if (lane == 0) {
        float d = dinv[node];
        *(float4*)(dxw1 + (size_t)node * 4) =
            make_float4(d * a[0], d * a[1], d * a[2], d * a[3]);
    }
}

__global__ __launch_bounds__(TPB) void k_gather44(
    const unsigned int* __restrict__ indptr, const int* __restrict__ csr_row,
    const float* __restrict__ dinv, const float* __restrict__ dxw_in,
    const float* __restrict__ b, const float* __restrict__ W,
    float* __restrict__ dxw_out, int N) {
    int gid  = blockIdx.x * TPB + threadIdx.x;
    int node = gid >> 4;
    int sub  = gid & 15;
    if (node >= N) return;
    int e0 = (int)indptr[node], e1 = (int)indptr[node + 1];
    float4 acc = make_float4(0.f, 0.f, 0.f, 0.f);
    for (int j = e0 + sub; j < e1; j += 16) {
        int r = csr_row[j];
        float4 m = *(const float4*)(dxw_in + (size_t)r * 4);
        acc.x += m.x; acc.y += m.y; acc.z += m.z; acc.w += m.w;
    }
#pragma unroll
    for (int off = 1; off < 16; off <<= 1) {
        acc.x += __shfl_xor(acc.x, off);
        acc.y += __shfl_xor(acc.y, off);
        acc.z += __shfl_xor(acc.z, off);
        acc.w += __shfl_xor(acc.w, off);
    }
    if (sub == 0) {
        float d = dinv[node];
        float4 sv = *(const float4*)(dxw_in + (size_t)node * 4);
        float h0 = fmaxf(d * (acc.x + sv.x) + b[0], 0.f);
        float h1 = fmaxf(d * (acc.y + sv.y) + b[1], 0.f);
        float h2 = fmaxf(d * (acc.z + sv.z) + b[2], 0.f);
        float h3 = fmaxf(d * (acc.w + sv.w) + b[3], 0.f);
        float o[4];
#pragma unroll
        for (int j = 0; j < 4; ++j)
            o[j] = h0 * W[0 * 4 + j] + h1 * W[1 * 4 + j] +
                   h2 * W[2 * 4 + j] + h3 * W[3 * 4 + j];
        *(float4*)(dxw_out + (size_t)node * 4) =
            make_float4(d * o[0], d * o[1], d * o[2], d * o[3]);
    }
}

__global__ __launch_bounds__(TPB) void k_gather42(
    const unsigned int* __restrict__ indptr, const int* __restrict__ csr_row,
    const float* __restrict__ dinv, const float* __restrict__ dxw_in,
    const float* __restrict__ b, const float* __restrict__ W,
    float* __restrict__ dxw_out, int N) {
    int gid  = blockIdx.x * TPB + threadIdx.x;
    int node = gid >> 4;
    int sub  = gid & 15;
    if (node >= N) return;
    int e0 = (int)indptr[node], e1 = (int)indptr[node + 1];
    float4 acc = make_float4(0.f, 0.f, 0.f, 0.f);
    for (int j = e0 + sub; j < e1; j += 16) {
        int r = csr_row[j];
        float4 m = *(const float4*)(dxw_in + (size_t)r * 4);
        acc.x += m.x; acc.y += m.y; acc.z += m.z; acc.w += m.w;
    }
#pragma unroll
    for (int off = 1; off < 16; off <<= 1) {
        acc.x += __shfl_xor(acc.x, off);
        acc.y += __shfl_xor(acc.y, off);
        acc.z += __shfl_xor(acc.z, off);
        acc.w += __shfl_xor(acc.w, off);
    }
    if (sub == 0) {
        float d = dinv[node];
        float4 sv = *(const float4*)(dxw_in + (size_t)node * 4);
        float h0 = fmaxf(d * (acc.x + sv.x) + b[0], 0.f);
        float h1 = fmaxf(d * (acc.y + sv.y) + b[1], 0.f);
        float h2 = fmaxf(d * (acc.z + sv.z) + b[2], 0.f);
        float h3 = fmaxf(d * (acc.w + sv.w) + b[3], 0.f);
        float o0 = h0 * W[0] + h1 * W[2] + h2 * W[4] + h3 * W[6];
        float o1 = h0 * W[1] + h1 * W[3] + h2 * W[5] + h3 * W[7];
        *(float2*)(dxw_out + (size_t)node * 2) = make_float2(d * o0, d * o1);
    }
}

__global__ __launch_bounds__(TPB) void k_gather2out(
    const unsigned int* __restrict__ indptr, const int* __restrict__ csr_row,
    const float* __restrict__ dinv, const float* __restrict__ dxw3,
    const float* __restrict__ b3, const float* __restrict__ Wc,
    const float* __restrict__ bc,
    float* __restrict__ out, float* __restrict__ y3out, int N) {
    int gid  = blockIdx.x * TPB + threadIdx.x;
    int node = gid >> 4;
    int sub  = gid & 15;
    if (node >= N) return;
    int e0 = (int)indptr[node], e1 = (int)indptr[node + 1];
    float ax = 0.f, ay = 0.f;
    for (int j = e0 + sub; j < e1; j += 16) {
        int r = csr_row[j];
        float2 m = *(const float2*)(dxw3 + (size_t)r * 2);
        ax += m.x; ay += m.y;
    }
#pragma unroll
    for (int off = 1; off < 16; off <<= 1) {
        ax += __shfl_xor(ax, off);
        ay += __shfl_xor(ay, off);
    }
    if (sub == 0) {
        float d = dinv[node];
        float2 sv = *(const float2*)(dxw3 + (size_t)node * 2);
        float y0 = fmaxf(d * (ax + sv.x) + b3[0], 0.f);
        float y1 = fmaxf(d * (ay + sv.y) + b3[1], 0.f);
        float o[4];
#pragma unroll
        for (int j = 0; j < 4; ++j)
            o[j] = y0 * Wc[0 * 4 + j] + y1 * Wc[1 * 4 + j] + bc[j];
        *(float4*)(out + (size_t)node * 4) = make_float4(o[0], o[1], o[2], o[3]);
        *(float2*)(y3out + (size_t)node * 2) = make_float2(y0, y1);
    }
}

// ---------------- R3 fallback kernels (atomic push path) ----------------

__global__ __launch_bounds__(TPB) void k_zero_deg(unsigned int* __restrict__ deg, int N) {
    int i = blockIdx.x * TPB + threadIdx.x;
    if (i < N) deg[i] = 0u;
}

__global__ __launch_bounds__(TPB) void k_deg(
    const int* __restrict__ col, unsigned int* __restrict__ deg, int E) {
    int e = blockIdx.x * TPB + threadIdx.x;
    if (e >= E) return;
    atomicAdd(&deg[col[e]], 1u);
}

__global__ __launch_bounds__(TPB) void k_dinv(const unsigned int* __restrict__ deg,
                                              float* __restrict__ dinv, int N) {
    int i = blockIdx.x * TPB + threadIdx.x;
    if (i < N) dinv[i] = rsqrtf((float)(deg[i] + 1u));
}

__global__ __launch_bounds__(TPB) void k_xw1(
    const float* __restrict__ x, const float* __restrict__ W1,
    const float* __restrict__ dinv,
    float* __restrict__ xw, float* __restrict__ agg, int N) {
    __shared__ float sW[512];
    for (int t = threadIdx.x; t < 512; t += TPB) sW[t] = W1[t];
    __syncthreads();
    int gid  = blockIdx.x * TPB + threadIdx.x;
    int node = gid >> 6;
    int lane = threadIdx.x & 63;
    if (node >= N) return;
    float2 v = *(const float2*)(x + (size_t)node * 128 + 2 * lane);
    const float* w0 = &sW[(2 * lane) * 4];
    const float* w1 = &sW[(2 * lane + 1) * 4];
    float a[4];
#pragma unroll
    for (int j = 0; j < 4; ++j) a[j] = v.x * w0[j] + v.y * w1[j];
#pragma unroll
    for (int off = 32; off > 0; off >>= 1) {
#pragma unroll
        for (int j = 0; j < 4; ++j) a[j] += __shfl_down(a[j], off);
    }
    if (lane == 0) {
        float d  = dinv[node];
        float d2 = d * d;
        *(float4*)(xw  + (size_t)node * 4) = make_float4(a[0], a[1], a[2], a[3]);
        *(float4*)(agg + (size_t)node * 4) =
            make_float4(d2 * a[0], d2 * a[1], d2 * a[2], d2 * a[3]);
    }
}

__global__ __launch_bounds__(TPB) void k_prop4(
    const int* __restrict__ row, const int* __restrict__ col,
    const float* __restrict__ dinv,
    const float* __restrict__ xw, float* __restrict__ agg, int E) {
    int e = blockIdx.x * TPB + threadIdx.x;
    if (e >= E) return;
    int r = row[e];
    int c = col[e];
    float nv = dinv[r] * dinv[c];
    float4 m = *(const float4*)(xw + (size_t)r * 4);
    float* a = agg + (size_t)c * 4;
    atomicAdd(a + 0, nv * m.x);
    atomicAdd(a + 1, nv * m.y);
    atomicAdd(a + 2, nv * m.z);
    atomicAdd(a + 3, nv * m.w);
}

__global__ __launch_bounds__(TPB) void k_prop2(
    const int* __restrict__ row, const int* __restrict__ col,
    const float* __restrict__ dinv,
    const float* __restrict__ xw2, float* __restrict__ agg2, int E) {
    int e = blockIdx.x * TPB + threadIdx.x;
    if (e >= E) return;
    int r = row[e];
    int c = col[e];
    float nv = dinv[r] * dinv[c];
    float2 m = *(const float2*)(xw2 + (size_t)r * 2);
    float* a = agg2 + (size_t)c * 2;
    atomicAdd(a + 0, nv * m.x);
    atomicAdd(a + 1, nv * m.y);
}

__global__ __launch_bounds__(TPB) void k_node2(
    const float* __restrict__ b1, const float* __restrict__ W2,
    const float* __restrict__ dinv,
    float* __restrict__ xw, float* __restrict__ agg, int N) {
    int i = blockIdx.x * TPB + threadIdx.x;
    if (i >= N) return;
    float4 av = *(const float4*)(agg + (size_t)i * 4);
    float h0 = fmaxf(av.x + b1[0], 0.f);
    float h1 = fmaxf(av.y + b1[1], 0.f);
    float h2 = fmaxf(av.z + b1[2], 0.f);
    float h3 = fmaxf(av.w + b1[3], 0.f);
    float o[4];
#pragma unroll
    for (int j = 0; j < 4; ++j)
        o[j] = h0 * W2[0 * 4 + j] + h1 * W2[1 * 4 + j] +
               h2 * W2[2 * 4 + j] + h3 * W2[3 * 4 + j];
    float d  = dinv[i];
    float d2 = d * d;
    *(float4*)(xw  + (size_t)i * 4) = make_float4(o[0], o[1], o[2], o[3]);
    *(float4*)(agg + (size_t)i * 4) = make_float4(d2 * o[0], d2 * o[1], d2 * o[2], d2 * o[3]);
}

__global__ __launch_bounds__(TPB) void k_node3(
    const float* __restrict__ b2, const float* __restrict__ W3,
    const float* __restrict__ dinv,
    const float* __restrict__ agg,
    float* __restrict__ xw3, float* __restrict__ agg3, int N) {
    int i = blockIdx.x * TPB + threadIdx.x;
    if (i >= N) return;
    float4 av = *(const float4*)(agg + (size_t)i * 4);
    float h0 = fmaxf(av.x + b2[0], 0.f);
    float h1 = fmaxf(av.y + b2[1], 0.f);
    float h2 = fmaxf(av.z + b2[2], 0.f);
    float h3 = fmaxf(av.w + b2[3], 0.f);
    float o0 = h0 * W3[0] + h1 * W3[2] + h2 * W3[4] + h3 * W3[6];
    float o1 = h0 * W3[1] + h1 * W3[3] + h2 * W3[5] + h3 * W3[7];
    float d  = dinv[i];
    float d2 = d * d;
    *(float2*)(xw3  + (size_t)i * 2) = make_float2(o0, o1);
    *(float2*)(agg3 + (size_t)i * 2) = make_float2(d2 * o0, d2 * o1);
}

__global__ __launch_bounds__(TPB) void k_out(
    const float* __restrict__ b3, const float* __restrict__ Wc,
    const float* __restrict__ bc,
    const float* __restrict__ agg3,
    float* __restrict__ out, float* __restrict__ y3out, int N) {
    int i = blockIdx.x * TPB + threadIdx.x;
    if (i >= N) return;
    float2 av = *(const float2*)(agg3 + (size_t)i * 2);
    float y0 = fmaxf(av.x + b3[0], 0.f);
    float y1 = fmaxf(av.y + b3[1], 0.f);
    float o[4];
#pragma unroll
    for (int j = 0; j < 4; ++j)
        o[j] = y0 * Wc[0 * 4 + j] + y1 * Wc[1 * 4 + j] + bc[j];
    *(float4*)(out + (size_t)i * 4) = make_float4(o[0], o[1], o[2], o[3]);
    *(float2*)(y3out + (size_t)i * 2) = make_float2(y0, y1);
}

extern "C" void kernel_launch(void* const* d_in, const int* in_sizes, int n_in,
                              void* d_out, int out_size, void* d_ws, size_t ws_size,
                              hipStream_t stream) {
    const float* x  = (const float*)d_in[0];
    const int*   ei = (const int*)d_in[1];   // int32 (harness converts integer inputs)
    const float* W1 = (const float*)d_in[2];
    const float* b1 = (const float*)d_in[3];
    const float* W2 = (const float*)d_in[4];
    const float* b2 = (const float*)d_in[5];
    const float* W3 = (const float*)d_in[6];
    const float* b3 = (const float*)d_in[7];
    const float* Wc = (const float*)d_in[8];
    const float* bc = (const float*)d_in[9];

    const int N = in_sizes[0] / 128;
    const int E = in_sizes[1] / 2;

    const int* row = ei;
    const int* col = ei + (size_t)E;

    const int NB  = (N + SPAN - 1) / SPAN;        // dest buckets (196)
    const int M   = NB * PART_B;                  // flattened hist size (~50K)
    const int PBE = (E + PART_B - 1) / PART_B;    // edges per partition block

    float* out   = (float*)d_out;                  // [N,4]
    float* y3out = (float*)d_out + (size_t)N * 4;  // [N,2]

    const int nblkN = (N + TPB - 1) / TPB;
    const int nblkE = (E + TPB - 1) / TPB;
    const int nblkW = (N * 64 + TPB - 1) / TPB;    // wave-per-node
    const int nblkG = (N * 16 + TPB - 1) / TPB;    // 16 threads/node
    const int nblkM = (M + 1 + TPB - 1) / TPB;
    const int nblkS = (M + SCAN_B - 1) / SCAN_B;   // scan blocks (~13)

    // Carve (~56.2MB). H is scanned in place (becomes O).
    size_t off = 0;
    auto carve = [&](size_t bytes) -> void* {
        void* r = (void*)((char*)d_ws + off);
        off += (bytes + 255) & ~(size_t)255;
        return r;
    };
    float*        dinv    = (float*)carve((size_t)N * 4);
    float*        dxw1    = (float*)carve((size_t)N * 4 * 4);
    float*        dxw2    = (float*)carve((size_t)N * 4 * 4);
    float*        dxw3    = (float*)carve((size_t)N * 2 * 4);
    unsigned int* indptr  = (unsigned int*)carve(((size_t)N + 1) * 4);
    uint32_t*     bsum    = (uint32_t*)carve(260 * 4);
    uint32_t*     H       = (uint32_t*)carve(((size_t)M + 1) * 4);  // -> O in place
    uint32_t*     bpack   = (uint32_t*)carve((size_t)E * 4);
    int*          csr_row = (int*)carve((size_t)E * 4);
    bool use_bucket = (off <= ws_size) && (NB <= 1024) && (N < (1 << 23));

    if (use_bucket) {
        size_t sort_lds = (size_t)SORT_CAP * 4;  // 140KB dynamic (+4KB static)
        hipFuncSetAttribute((const void*)p_sort,
                            hipFuncAttributeMaxDynamicSharedMemorySize,
                            (int)sort_lds);
        p_hist<<<PART_B, PART_T, 0, stream>>>(col, H, NB, E, PBE);
        k_scan1<<<nblkS, SCAN_T, 0, stream>>>(H, H, bsum, M);         // in-place
        k_scan2<<<1, 32, 0, stream>>>(bsum, nblkS);
        k_scan3<<<nblkM, TPB, 0, stream>>>(H, bsum, H, M, E);         // in-place
        p_part<<<PART_B, PART_T, 0, stream>>>(row, col, H, bpack, NB, E, PBE);
        p_sort<<<NB, PART_T, sort_lds, stream>>>(bpack, H, csr_row, indptr,
                                                 dinv, NB, N, E);
        k_xw1d<<<nblkW, TPB, 0, stream>>>(x, W1, dinv, dxw1, N);
        k_gather44<<<nblkG, TPB, 0, stream>>>(indptr, csr_row, dinv, dxw1, b1, W2, dxw2, N);
        k_gather42<<<nblkG, TPB, 0, stream>>>(indptr, csr_row, dinv, dxw2, b2, W3, dxw3, N);
        k_gather2out<<<nblkG, TPB, 0, stream>>>(indptr, csr_row, dinv, dxw3, b3, Wc, bc,
                                                out, y3out, N);
    } else {
        // R3 verified atomic-push fallback: recarve from base (~6MB).
        size_t foff = 0;
        auto fcarve = [&](size_t bytes) -> void* {
            void* r = (void*)((char*)d_ws + foff);
            foff += (bytes + 255) & ~(size_t)255;
            return r;
        };
        unsigned int* deg   = (unsigned int*)fcarve((size_t)N * 4);
        float*        fdinv = (float*)fcarve((size_t)N * 4);
        float*        xw    = (float*)fcarve((size_t)N * 4 * 4);
        float*        agg   = (float*)fcarve((size_t)N * 4 * 4);
        float*        xw3   = (float*)fcarve((size_t)N * 2 * 4);
        float*        agg3  = (float*)fcarve((size_t)N * 2 * 4);
        k_zero_deg<<<nblkN, TPB, 0, stream>>>(deg, N);
        k_deg<<<nblkE, TPB, 0, stream>>>(col, deg, E);
        k_dinv<<<nblkN, TPB, 0, stream>>>(deg, fdinv, N);
        k_xw1<<<nblkW, TPB, 0, stream>>>(x, W1, fdinv, xw, agg, N);
        k_prop4<<<nblkE, TPB, 0, stream>>>(row, col, fdinv, xw, agg, E);
        k_node2<<<nblkN, TPB, 0, stream>>>(b1, W2, fdinv, xw, agg, N);
        k_prop4<<<nblkE, TPB, 0, stream>>>(row, col, fdinv, xw, agg, E);
        k_node3<<<nblkN, TPB, 0, stream>>>(b2, W3, fdinv, agg, xw3, agg3, N);
        k_prop2<<<nblkE, TPB, 0, stream>>>(row, col, fdinv, xw3, agg3, E);
        k_out<<<nblkN, TPB, 0, stream>>>(b3, Wc, bc, agg3, out, y3out, N);
    }
}